// Round 8
// baseline (131.189 us; speedup 1.0000x reference)
//
#include <hip/hip_runtime.h>
#include <hip/hip_bf16.h>
#include <math.h>

#define H 64
#define W 64
#define CIN 128
#define COUT 128
#define BATCH 8
#define NPIX (H*W)      // 4096
#define PXT 32          // pixels per k_deform block
#define AP  136         // padded LDS pitch in bf16 elems (16B-aligned rows)

typedef __attribute__((ext_vector_type(8))) short bf16x8;
typedef __attribute__((ext_vector_type(4))) float f32x4;

static __device__ inline short f2bf(float f) {
  union { float f; unsigned u; } v; v.f = f;
  unsigned r = v.u + 0x7FFF + ((v.u >> 16) & 1);   // RNE
  return (short)(r >> 16);
}
static __device__ inline float bf_lo(unsigned u) {
  union { unsigned u; float f; } v; v.u = u << 16; return v.f;
}
static __device__ inline float bf_hi(unsigned u) {
  union { unsigned u; float f; } v; v.u = u & 0xffff0000u; return v.f;
}

// ---------------------------------------------------------------------------
// Kernel 1 (fused prep): [0,2048) transpose NCHW->BHWC bf16;
// [2048,2192) pack wOMs (A-frag swizzled, 32 oc zero-padded);
// [2192,2768) pack wAs (A-frag swizzled).
// ---------------------------------------------------------------------------
__global__ __launch_bounds__(256) void k_prep(const float* __restrict__ x,
    short* __restrict__ xbh,
    const float* __restrict__ w_off, const float* __restrict__ w_mod,
    short* __restrict__ wOMs, const float* __restrict__ w_reg,
    short* __restrict__ wAs) {
  __shared__ float tile[32][65];
  int blk = blockIdx.x;
  int t = threadIdx.x;
  if (blk < 2048) {                       // --- transpose ---
    int cg = blk & 3, y = (blk >> 2) & 63, b = blk >> 8;
#pragma unroll
    for (int j = 0; j < 8; ++j) {
      int idx = t + j * 256;
      int ci = idx >> 6, xi = idx & 63;
      tile[ci][xi] = x[(((b * CIN + cg * 32 + ci) * H + y) * W) + xi];
    }
    __syncthreads();
#pragma unroll
    for (int j = 0; j < 8; ++j) {
      int idx = t + j * 256;
      int xi = idx >> 5, ci = idx & 31;
      xbh[((b * H + y) * W + xi) * CIN + cg * 32 + ci] = f2bf(tile[ci][xi]);
    }
  } else if (blk < 2048 + 144) {          // --- wOMs pack (swizzled) ---
    int e = (blk - 2048) * 256 + t;       // tap*4096 + oc*128 + c  (36864)
    int tap = e >> 12, oc = (e >> 7) & 31, c = e & 127;
    float v = 0.f;
    if (oc < 18)      v = w_off[(oc * 128 + c) * 9 + tap];
    else if (oc < 27) v = w_mod[((oc - 18) * 128 + c) * 9 + tap];
    int kb = c >> 5, quad = (c >> 3) & 3, j = c & 7;
    int g = oc >> 4, l16 = oc & 15;
    int o = ((tap * 4 + kb) * 2 + g) * 512 + (quad * 16 + l16) * 8 + j;
    wOMs[o] = f2bf(v);
  } else {                                // --- wAs pack (swizzled) ---
    int e = (blk - 2192) * 256 + t;       // tap*16384 + oc*128 + c
    int tap = e >> 14, oc = (e >> 7) & 127, c = e & 127;
    int kb = c >> 5, quad = (c >> 3) & 3, j = c & 7;
    int g = oc >> 4, l16 = oc & 15;
    int o = ((tap * 4 + kb) * 8 + g) * 512 + (quad * 16 + l16) * 8 + j;
    wAs[o] = f2bf(w_reg[(oc * 128 + c) * 9 + tap]);
  }
}

// ---------------------------------------------------------------------------
// Kernel 2: FUSED offset/mask conv + deformable conv.  512 threads, 8 waves.
// Phase 1 (offmask): wave w computes taps {w, w+8} of the 32oc x 32px x 1152
//   mini-GEMM; A from wOMs (contiguous frags), B gathered directly from xbh
//   im2col (16B/lane, zeroed at pads).  Partials -> red[] -> pw/pa (sigmoid
//   fused).  No pym global round-trip.
// Phase 2 (deform): as R7 — bilinear bf16x4 sampling + MFMA.
// MFMA layouts (m89/m91): A[m=l16][k=quad*8+j], B[k=quad*8+j][n=l16],
//   D[m=quad*4+r][n=l16].
// ---------------------------------------------------------------------------
__global__ __launch_bounds__(512) void k_deform(const short* __restrict__ xbh,
    const short* __restrict__ wOMs, const float* __restrict__ b_off,
    const float* __restrict__ b_mod, const short* __restrict__ wAs,
    float* __restrict__ out) {
  __shared__ float red[8 * 1024];                 // 32 KB phase-1 partials
  __shared__ __align__(16) short vs[PXT * AP];    //  8.7 KB
  __shared__ __align__(16) float pw[PXT * 9 * 4]; //  4.6 KB {w00,w01,w10,w11}
  __shared__ __align__(16) int   pa[PXT * 9 * 4]; //  4.6 KB {a00,a01,a10,a11}

  int blk = blockIdx.x;
  int b = blk & 7, tile = blk >> 3;               // XCD swizzle
  int pix0 = tile * PXT;
  int t = threadIdx.x;
  int lane = t & 63;
  int wv = t >> 6;                                // 0..7
  int l16 = lane & 15, quad = lane >> 4;

  const short* xbB = xbh + (size_t)b * NPIX * CIN;

  // ===== Phase 1: offset/mask mini-GEMM (tap-parallel across waves) =====
  {
    f32x4 acc_o[2][2] = {};
    for (int tap = wv; tap < 9; tap += 8) {       // wave 0: taps 0 and 8
      const short* wt = wOMs + tap * 4096;
      int dy = tap / 3 - 1, dx = tap % 3 - 1;
      // pixel linear addresses for the two n-frags (per lane)
      int lin[2], val[2];
#pragma unroll
      for (int nt = 0; nt < 2; ++nt) {
        int gp = pix0 + nt * 16 + l16;
        int y = (gp >> 6) + dy, x = (gp & 63) + dx;
        int ok = ((unsigned)y < H) && ((unsigned)x < W);
        val[nt] = ok;
        lin[nt] = ok ? ((y << 6) + x) : 0;
      }
#pragma unroll
      for (int kb = 0; kb < 4; ++kb) {
        bf16x8 a0 = *(const bf16x8*)&wt[(kb * 2 + 0) * 512 + lane * 8];
        bf16x8 a1 = *(const bf16x8*)&wt[(kb * 2 + 1) * 512 + lane * 8];
#pragma unroll
        for (int nt = 0; nt < 2; ++nt) {
          bf16x8 bv = *(const bf16x8*)&xbB[(size_t)lin[nt] * CIN + kb * 32 + quad * 8];
          if (!val[nt]) bv = (bf16x8){};
          acc_o[0][nt] = __builtin_amdgcn_mfma_f32_16x16x32_bf16(a0, bv, acc_o[0][nt], 0, 0, 0);
          acc_o[1][nt] = __builtin_amdgcn_mfma_f32_16x16x32_bf16(a1, bv, acc_o[1][nt], 0, 0, 0);
        }
      }
    }
    // partials -> red[wv][oc][px]
#pragma unroll
    for (int mt = 0; mt < 2; ++mt)
#pragma unroll
      for (int nt = 0; nt < 2; ++nt)
#pragma unroll
        for (int r = 0; r < 4; ++r) {
          int oc = mt * 16 + quad * 4 + r;
          int px = nt * 16 + l16;
          red[wv * 1024 + oc * 32 + px] = acc_o[mt][nt][r];
        }
  }
  __syncthreads();

  // ===== reduce 8 partials + bias + sigmoid -> pw / pa =====
  for (int i = t; i < PXT * 9; i += 512) {        // i = p*9 + tap
    int tap = i % 9, p = i / 9;
    float dyv = b_off[2 * tap], dxv = b_off[2 * tap + 1], z = b_mod[tap];
#pragma unroll
    for (int w = 0; w < 8; ++w) {
      dyv += red[w * 1024 + (2 * tap) * 32 + p];
      dxv += red[w * 1024 + (2 * tap + 1) * 32 + p];
      z   += red[w * 1024 + (18 + tap) * 32 + p];
    }
    float m = 2.f / (1.f + expf(-z));
    int gp = pix0 + p;
    float py = (float)((gp >> 6) - 1 + tap / 3) + dyv;
    float pxx = (float)((gp & 63) - 1 + tap % 3) + dxv;
    float yf = floorf(py), xf = floorf(pxx);
    float wy = py - yf, wx = pxx - xf;
    int y0 = (int)yf, x0 = (int)xf;
    int y1 = y0 + 1, x1 = x0 + 1;
    float vy0 = ((unsigned)y0 < H) ? 1.f : 0.f;
    float vy1 = ((unsigned)y1 < H) ? 1.f : 0.f;
    float vx0 = ((unsigned)x0 < W) ? 1.f : 0.f;
    float vx1 = ((unsigned)x1 < W) ? 1.f : 0.f;
    int y0c = min(max(y0, 0), H - 1), y1c = min(max(y1, 0), H - 1);
    int x0c = min(max(x0, 0), W - 1), x1c = min(max(x1, 0), W - 1);
    *(float4*)&pw[i * 4] = make_float4((1.f - wy) * (1.f - wx) * m * vy0 * vx0,
                                       (1.f - wy) * wx * m * vy0 * vx1,
                                       wy * (1.f - wx) * m * vy1 * vx0,
                                       wy * wx * m * vy1 * vx1);
    *(int4*)&pa[i * 4] = make_int4(((y0c << 6) + x0c) << 7,
                                   ((y0c << 6) + x1c) << 7,
                                   ((y1c << 6) + x0c) << 7,
                                   ((y1c << 6) + x1c) << 7);
  }

  // ===== Phase 2: main deformable GEMM (as R7) =====
  int ms = wv & 3, nh = wv >> 2;          // oc-slice, px-half
  int cq = t & 31, pxsub = (t >> 5) & 1, grp = t >> 6;
  int c0 = cq * 4;

  f32x4 acc[2] = {};

  for (int tap = 0; tap < 9; ++tap) {
    __syncthreads();   // tap0: pw/pa visible; else: prev vs consumed

    // A frags (prefetch; in flight during sampling)
    const short* wtap = wAs + tap * 16384;
    bf16x8 af0[4], af1[4];
#pragma unroll
    for (int kb = 0; kb < 4; ++kb) {
      af0[kb] = *(const bf16x8*)&wtap[(kb * 8 + ms * 2) * 512 + lane * 8];
      af1[kb] = *(const bf16x8*)&wtap[(kb * 8 + ms * 2 + 1) * 512 + lane * 8];
    }

    // sample B tile: 2 iters x (4 corners x 4 ch) per thread
#pragma unroll
    for (int i = 0; i < 2; ++i) {
      int p = grp * 4 + i * 2 + pxsub;
      int idx = (p * 9 + tap) * 4;
      float4 wq = *(const float4*)&pw[idx];
      int4 aa = *(const int4*)&pa[idx];
      uint2 u00 = *(const uint2*)&xbB[aa.x + c0];
      uint2 u01 = *(const uint2*)&xbB[aa.y + c0];
      uint2 u10 = *(const uint2*)&xbB[aa.z + c0];
      uint2 u11 = *(const uint2*)&xbB[aa.w + c0];
      float s0 = wq.x * bf_lo(u00.x), s1 = wq.x * bf_hi(u00.x);
      float s2 = wq.x * bf_lo(u00.y), s3 = wq.x * bf_hi(u00.y);
      s0 = fmaf(wq.y, bf_lo(u01.x), s0); s1 = fmaf(wq.y, bf_hi(u01.x), s1);
      s2 = fmaf(wq.y, bf_lo(u01.y), s2); s3 = fmaf(wq.y, bf_hi(u01.y), s3);
      s0 = fmaf(wq.z, bf_lo(u10.x), s0); s1 = fmaf(wq.z, bf_hi(u10.x), s1);
      s2 = fmaf(wq.z, bf_lo(u10.y), s2); s3 = fmaf(wq.z, bf_hi(u10.y), s3);
      s0 = fmaf(wq.w, bf_lo(u11.x), s0); s1 = fmaf(wq.w, bf_hi(u11.x), s1);
      s2 = fmaf(wq.w, bf_lo(u11.y), s2); s3 = fmaf(wq.w, bf_hi(u11.y), s3);
      __hip_bfloat162 h2a = __float22bfloat162_rn(make_float2(s0, s1));
      __hip_bfloat162 h2b = __float22bfloat162_rn(make_float2(s2, s3));
      uint2 packed;
      packed.x = *(unsigned*)&h2a;
      packed.y = *(unsigned*)&h2b;
      *(uint2*)&vs[p * AP + c0] = packed;
    }
    __syncthreads();

    // MFMA: 4 k-steps, 2 m-tiles x 1 n-tile per wave
#pragma unroll
    for (int kb = 0; kb < 4; ++kb) {
      int kcol = kb * 32 + quad * 8;
      bf16x8 b0 = *(const bf16x8*)&vs[(nh * 16 + l16) * AP + kcol];
      acc[0] = __builtin_amdgcn_mfma_f32_16x16x32_bf16(af0[kb], b0, acc[0], 0, 0, 0);
      acc[1] = __builtin_amdgcn_mfma_f32_16x16x32_bf16(af1[kb], b0, acc[1], 0, 0, 0);
    }
  }

  // epilogue: D[m=quad*4+r][n=l16] -> out[b][oc][pix]
  int oc_base = ms * 32;
#pragma unroll
  for (int mt = 0; mt < 2; ++mt)
#pragma unroll
    for (int r = 0; r < 4; ++r) {
      int oc = oc_base + mt * 16 + quad * 4 + r;
      int px = nh * 16 + l16;
      out[(size_t)(b * COUT + oc) * NPIX + pix0 + px] = acc[mt][r];
    }
}

// ---------------------------------------------------------------------------
extern "C" void kernel_launch(void* const* d_in, const int* in_sizes, int n_in,
                              void* d_out, int out_size, void* d_ws, size_t ws_size,
                              hipStream_t stream) {
  const float* x     = (const float*)d_in[0];
  const float* w_off = (const float*)d_in[1];
  const float* b_off = (const float*)d_in[2];
  const float* w_mod = (const float*)d_in[3];
  const float* b_mod = (const float*)d_in[4];
  const float* w_reg = (const float*)d_in[5];

  short* xbh  = (short*)d_ws;              // 4,194,304 bf16 (8 MB)
  short* wAs  = xbh + 4194304;             //   147,456 bf16 (swizzled)
  short* wOMs = wAs + 147456;              //    36,864 bf16 (swizzled)
  float* out  = (float*)d_out;

  k_prep<<<dim3(2768), 256, 0, stream>>>(x, xbh, w_off, w_mod, wOMs,
                                         w_reg, wAs);
  k_deform<<<dim3(NPIX / PXT * BATCH), 512, 0, stream>>>(
      xbh, wOMs, b_off, b_mod, wAs, out);
}

// Round 9
// 117.443 us; speedup vs baseline: 1.1170x; 1.1170x over previous
//
#include <hip/hip_runtime.h>
#include <hip/hip_bf16.h>
#include <math.h>

#define H 64
#define W 64
#define CIN 128
#define COUT 128
#define BATCH 8
#define NPIX (H*W)      // 4096
#define PXT 32          // pixels per k_deform block
#define AP  136         // padded LDS pitch in bf16 elems (16B-aligned rows)
#define RP  36          // red pitch (floats): quad stride 144 ≡ 16 mod 32 -> 2-way
#define VSZ (PXT*AP)    // one vs buffer in shorts (4352)

typedef __attribute__((ext_vector_type(8))) short bf16x8;
typedef __attribute__((ext_vector_type(4))) float f32x4;

static __device__ inline short f2bf(float f) {
  union { float f; unsigned u; } v; v.f = f;
  unsigned r = v.u + 0x7FFF + ((v.u >> 16) & 1);   // RNE
  return (short)(r >> 16);
}
static __device__ inline float bf_lo(unsigned u) {
  union { unsigned u; float f; } v; v.u = u << 16; return v.f;
}
static __device__ inline float bf_hi(unsigned u) {
  union { unsigned u; float f; } v; v.u = u & 0xffff0000u; return v.f;
}

// ---------------------------------------------------------------------------
// Kernel 1 (fused prep): [0,2048) transpose NCHW->BHWC bf16;
// [2048,2192) pack wOMs (A-frag swizzled, 32 oc zero-padded);
// [2192,2768) pack wAs (A-frag swizzled).
// ---------------------------------------------------------------------------
__global__ __launch_bounds__(256) void k_prep(const float* __restrict__ x,
    short* __restrict__ xbh,
    const float* __restrict__ w_off, const float* __restrict__ w_mod,
    short* __restrict__ wOMs, const float* __restrict__ w_reg,
    short* __restrict__ wAs) {
  __shared__ float tile[32][65];
  int blk = blockIdx.x;
  int t = threadIdx.x;
  if (blk < 2048) {                       // --- transpose ---
    int cg = blk & 3, y = (blk >> 2) & 63, b = blk >> 8;
#pragma unroll
    for (int j = 0; j < 8; ++j) {
      int idx = t + j * 256;
      int ci = idx >> 6, xi = idx & 63;
      tile[ci][xi] = x[(((b * CIN + cg * 32 + ci) * H + y) * W) + xi];
    }
    __syncthreads();
#pragma unroll
    for (int j = 0; j < 8; ++j) {
      int idx = t + j * 256;
      int xi = idx >> 5, ci = idx & 31;
      xbh[((b * H + y) * W + xi) * CIN + cg * 32 + ci] = f2bf(tile[ci][xi]);
    }
  } else if (blk < 2048 + 144) {          // --- wOMs pack (swizzled) ---
    int e = (blk - 2048) * 256 + t;       // tap*4096 + oc*128 + c  (36864)
    int tap = e >> 12, oc = (e >> 7) & 31, c = e & 127;
    float v = 0.f;
    if (oc < 18)      v = w_off[(oc * 128 + c) * 9 + tap];
    else if (oc < 27) v = w_mod[((oc - 18) * 128 + c) * 9 + tap];
    int kb = c >> 5, quad = (c >> 3) & 3, j = c & 7;
    int g = oc >> 4, l16 = oc & 15;
    int o = ((tap * 4 + kb) * 2 + g) * 512 + (quad * 16 + l16) * 8 + j;
    wOMs[o] = f2bf(v);
  } else {                                // --- wAs pack (swizzled) ---
    int e = (blk - 2192) * 256 + t;       // tap*16384 + oc*128 + c
    int tap = e >> 14, oc = (e >> 7) & 127, c = e & 127;
    int kb = c >> 5, quad = (c >> 3) & 3, j = c & 7;
    int g = oc >> 4, l16 = oc & 15;
    int o = ((tap * 4 + kb) * 8 + g) * 512 + (quad * 16 + l16) * 8 + j;
    wAs[o] = f2bf(w_reg[(oc * 128 + c) * 9 + tap]);
  }
}

// ---------------------------------------------------------------------------
// Kernel 2: FUSED offset/mask conv + deformable conv.  512 threads, 8 waves.
// R9: (a) red (27 rows, pitch 36, 2-way banks) UNIONed with double-buffered
// vs -> LDS 50688 -> 40320 B -> 4 blocks/CU (needs VGPR<=64, forced by
// __launch_bounds__(512,8)); (b) one barrier per tap (vs double-buffer);
// (c) 8-ch bf16x8 sampling gathers + single ds_write_b128.
// MFMA layouts (m89/m91): A[m=l16][k=quad*8+j], B[k=quad*8+j][n=l16],
//   D[m=quad*4+r][n=l16].
// ---------------------------------------------------------------------------
__global__ __launch_bounds__(512, 8) void k_deform(const short* __restrict__ xbh,
    const short* __restrict__ wOMs, const float* __restrict__ b_off,
    const float* __restrict__ b_mod, const short* __restrict__ wAs,
    float* __restrict__ out) {
  // red: 8 waves x 27 oc x pitch 36 floats = 31104 B
  // vs : 2 buffers x 32 px x 136 shorts    = 17408 B  (aliased into smem_u)
  __shared__ __align__(16) char smem_u[31104];
  __shared__ __align__(16) float pw[PXT * 9 * 4]; // 4608 B {w00,w01,w10,w11}
  __shared__ __align__(16) int   pa[PXT * 9 * 4]; // 4608 B {a00,a01,a10,a11}
  float* red = (float*)smem_u;
  short* vs  = (short*)smem_u;

  int blk = blockIdx.x;
  int b = blk & 7, tile = blk >> 3;               // XCD swizzle
  int pix0 = tile * PXT;
  int t = threadIdx.x;
  int lane = t & 63;
  int wv = t >> 6;                                // 0..7
  int l16 = lane & 15, quad = lane >> 4;

  const short* xbB = xbh + (size_t)b * NPIX * CIN;

  // ===== Phase 1: offset/mask mini-GEMM (tap-parallel across waves) =====
  {
    f32x4 acc_o[2][2] = {};
    for (int tap = wv; tap < 9; tap += 8) {       // wave 0: taps 0 and 8
      const short* wt = wOMs + tap * 4096;
      int dy = tap / 3 - 1, dx = tap % 3 - 1;
      int lin[2], val[2];
#pragma unroll
      for (int nt = 0; nt < 2; ++nt) {
        int gp = pix0 + nt * 16 + l16;
        int y = (gp >> 6) + dy, x = (gp & 63) + dx;
        int ok = ((unsigned)y < H) && ((unsigned)x < W);
        val[nt] = ok;
        lin[nt] = ok ? ((y << 6) + x) : 0;
      }
#pragma unroll
      for (int kb = 0; kb < 4; ++kb) {
        bf16x8 a0 = *(const bf16x8*)&wt[(kb * 2 + 0) * 512 + lane * 8];
        bf16x8 a1 = *(const bf16x8*)&wt[(kb * 2 + 1) * 512 + lane * 8];
#pragma unroll
        for (int nt = 0; nt < 2; ++nt) {
          bf16x8 bv = *(const bf16x8*)&xbB[(size_t)lin[nt] * CIN + kb * 32 + quad * 8];
          if (!val[nt]) bv = (bf16x8){};
          acc_o[0][nt] = __builtin_amdgcn_mfma_f32_16x16x32_bf16(a0, bv, acc_o[0][nt], 0, 0, 0);
          acc_o[1][nt] = __builtin_amdgcn_mfma_f32_16x16x32_bf16(a1, bv, acc_o[1][nt], 0, 0, 0);
        }
      }
    }
    // partials -> red[wv][oc][px]  (only oc<27 used)
#pragma unroll
    for (int mt = 0; mt < 2; ++mt)
#pragma unroll
      for (int nt = 0; nt < 2; ++nt)
#pragma unroll
        for (int r = 0; r < 4; ++r) {
          int oc = mt * 16 + quad * 4 + r;
          if (oc < 27) {
            int px = nt * 16 + l16;
            red[wv * (27 * RP) + oc * RP + px] = acc_o[mt][nt][r];
          }
        }
  }
  __syncthreads();

  // ===== reduce 8 partials + bias + sigmoid -> pw / pa =====
  for (int i = t; i < PXT * 9; i += 512) {        // i = p*9 + tap
    int tap = i % 9, p = i / 9;
    float dyv = b_off[2 * tap], dxv = b_off[2 * tap + 1], z = b_mod[tap];
#pragma unroll
    for (int w = 0; w < 8; ++w) {
      const float* rw = red + w * (27 * RP);
      dyv += rw[(2 * tap) * RP + p];
      dxv += rw[(2 * tap + 1) * RP + p];
      z   += rw[(18 + tap) * RP + p];
    }
    float m = 2.f / (1.f + expf(-z));
    int gp = pix0 + p;
    float py = (float)((gp >> 6) - 1 + tap / 3) + dyv;
    float pxx = (float)((gp & 63) - 1 + tap % 3) + dxv;
    float yf = floorf(py), xf = floorf(pxx);
    float wy = py - yf, wx = pxx - xf;
    int y0 = (int)yf, x0 = (int)xf;
    int y1 = y0 + 1, x1 = x0 + 1;
    float vy0 = ((unsigned)y0 < H) ? 1.f : 0.f;
    float vy1 = ((unsigned)y1 < H) ? 1.f : 0.f;
    float vx0 = ((unsigned)x0 < W) ? 1.f : 0.f;
    float vx1 = ((unsigned)x1 < W) ? 1.f : 0.f;
    int y0c = min(max(y0, 0), H - 1), y1c = min(max(y1, 0), H - 1);
    int x0c = min(max(x0, 0), W - 1), x1c = min(max(x1, 0), W - 1);
    *(float4*)&pw[i * 4] = make_float4((1.f - wy) * (1.f - wx) * m * vy0 * vx0,
                                       (1.f - wy) * wx * m * vy0 * vx1,
                                       wy * (1.f - wx) * m * vy1 * vx0,
                                       wy * wx * m * vy1 * vx1);
    *(int4*)&pa[i * 4] = make_int4(((y0c << 6) + x0c) << 7,
                                   ((y0c << 6) + x1c) << 7,
                                   ((y1c << 6) + x0c) << 7,
                                   ((y1c << 6) + x1c) << 7);
  }
  __syncthreads();   // pw/pa visible; all red reads done (vs may now alias)

  // ===== Phase 2: main deformable GEMM, double-buffered vs =====
  int ms = wv & 3, nh = wv >> 2;          // oc-slice, px-half
  int cq = t & 15, ps = t >> 4;           // 8-ch group, pixel (0..31)
  int c0 = cq * 8;

  f32x4 acc[2] = {};

  for (int tap = 0; tap < 9; ++tap) {
    short* vbuf = vs + (tap & 1) * VSZ;

    // --- sample: 1 px x 8 ch per thread, 4 corner gathers of 16 B ---
    {
      int idx = (ps * 9 + tap) * 4;
      float4 wq = *(const float4*)&pw[idx];
      int4 aa = *(const int4*)&pa[idx];
      uint4 u00 = *(const uint4*)&xbB[aa.x + c0];
      uint4 u01 = *(const uint4*)&xbB[aa.y + c0];
      uint4 u10 = *(const uint4*)&xbB[aa.z + c0];
      uint4 u11 = *(const uint4*)&xbB[aa.w + c0];
      float s0 = wq.x * bf_lo(u00.x), s1 = wq.x * bf_hi(u00.x);
      float s2 = wq.x * bf_lo(u00.y), s3 = wq.x * bf_hi(u00.y);
      float s4 = wq.x * bf_lo(u00.z), s5 = wq.x * bf_hi(u00.z);
      float s6 = wq.x * bf_lo(u00.w), s7 = wq.x * bf_hi(u00.w);
      s0 = fmaf(wq.y, bf_lo(u01.x), s0); s1 = fmaf(wq.y, bf_hi(u01.x), s1);
      s2 = fmaf(wq.y, bf_lo(u01.y), s2); s3 = fmaf(wq.y, bf_hi(u01.y), s3);
      s4 = fmaf(wq.y, bf_lo(u01.z), s4); s5 = fmaf(wq.y, bf_hi(u01.z), s5);
      s6 = fmaf(wq.y, bf_lo(u01.w), s6); s7 = fmaf(wq.y, bf_hi(u01.w), s7);
      s0 = fmaf(wq.z, bf_lo(u10.x), s0); s1 = fmaf(wq.z, bf_hi(u10.x), s1);
      s2 = fmaf(wq.z, bf_lo(u10.y), s2); s3 = fmaf(wq.z, bf_hi(u10.y), s3);
      s4 = fmaf(wq.z, bf_lo(u10.z), s4); s5 = fmaf(wq.z, bf_hi(u10.z), s5);
      s6 = fmaf(wq.z, bf_lo(u10.w), s6); s7 = fmaf(wq.z, bf_hi(u10.w), s7);
      s0 = fmaf(wq.w, bf_lo(u11.x), s0); s1 = fmaf(wq.w, bf_hi(u11.x), s1);
      s2 = fmaf(wq.w, bf_lo(u11.y), s2); s3 = fmaf(wq.w, bf_hi(u11.y), s3);
      s4 = fmaf(wq.w, bf_lo(u11.z), s4); s5 = fmaf(wq.w, bf_hi(u11.z), s5);
      s6 = fmaf(wq.w, bf_lo(u11.w), s6); s7 = fmaf(wq.w, bf_hi(u11.w), s7);
      __hip_bfloat162 h0 = __float22bfloat162_rn(make_float2(s0, s1));
      __hip_bfloat162 h1 = __float22bfloat162_rn(make_float2(s2, s3));
      __hip_bfloat162 h2 = __float22bfloat162_rn(make_float2(s4, s5));
      __hip_bfloat162 h3 = __float22bfloat162_rn(make_float2(s6, s7));
      uint4 packed;
      packed.x = *(unsigned*)&h0; packed.y = *(unsigned*)&h1;
      packed.z = *(unsigned*)&h2; packed.w = *(unsigned*)&h3;
      *(uint4*)&vbuf[ps * AP + c0] = packed;
    }

    // --- A frags prefetch (issued before barrier; waits only at MFMA) ---
    const short* wtap = wAs + tap * 16384;
    bf16x8 af0[4], af1[4];
#pragma unroll
    for (int kb = 0; kb < 4; ++kb) {
      af0[kb] = *(const bf16x8*)&wtap[(kb * 8 + ms * 2) * 512 + lane * 8];
      af1[kb] = *(const bf16x8*)&wtap[(kb * 8 + ms * 2 + 1) * 512 + lane * 8];
    }
    __syncthreads();   // vbuf writes visible; other buffer free for tap+1

    // --- MFMA: 4 k-steps, 2 m-tiles x 1 n-tile per wave ---
#pragma unroll
    for (int kb = 0; kb < 4; ++kb) {
      int kcol = kb * 32 + quad * 8;
      bf16x8 b0 = *(const bf16x8*)&vbuf[(nh * 16 + l16) * AP + kcol];
      acc[0] = __builtin_amdgcn_mfma_f32_16x16x32_bf16(af0[kb], b0, acc[0], 0, 0, 0);
      acc[1] = __builtin_amdgcn_mfma_f32_16x16x32_bf16(af1[kb], b0, acc[1], 0, 0, 0);
    }
  }

  // epilogue: D[m=quad*4+r][n=l16] -> out[b][oc][pix]
  int oc_base = ms * 32;
#pragma unroll
  for (int mt = 0; mt < 2; ++mt)
#pragma unroll
    for (int r = 0; r < 4; ++r) {
      int oc = oc_base + mt * 16 + quad * 4 + r;
      int px = nh * 16 + l16;
      out[(size_t)(b * COUT + oc) * NPIX + pix0 + px] = acc[mt][r];
    }
}

// ---------------------------------------------------------------------------
extern "C" void kernel_launch(void* const* d_in, const int* in_sizes, int n_in,
                              void* d_out, int out_size, void* d_ws, size_t ws_size,
                              hipStream_t stream) {
  const float* x     = (const float*)d_in[0];
  const float* w_off = (const float*)d_in[1];
  const float* b_off = (const float*)d_in[2];
  const float* w_mod = (const float*)d_in[3];
  const float* b_mod = (const float*)d_in[4];
  const float* w_reg = (const float*)d_in[5];

  short* xbh  = (short*)d_ws;              // 4,194,304 bf16 (8 MB)
  short* wAs  = xbh + 4194304;             //   147,456 bf16 (swizzled)
  short* wOMs = wAs + 147456;              //    36,864 bf16 (swizzled)
  float* out  = (float*)d_out;

  k_prep<<<dim3(2768), 256, 0, stream>>>(x, xbh, w_off, w_mod, wOMs,
                                         w_reg, wAs);
  k_deform<<<dim3(NPIX / PXT * BATCH), 512, 0, stream>>>(
      xbh, wOMs, b_off, b_mod, wAs, out);
}

// Round 10
// 116.546 us; speedup vs baseline: 1.1256x; 1.0077x over previous
//
#include <hip/hip_runtime.h>
#include <hip/hip_bf16.h>
#include <math.h>

#define H 64
#define W 64
#define CIN 128
#define COUT 128
#define BATCH 8
#define NPIX (H*W)      // 4096
#define PXT 64          // pixels per k_deform block (R10: 32 -> 64)
#define AP  136         // padded LDS pitch in bf16 elems (16B-aligned rows)
#define RP  36          // red pitch (floats)
#define VSZ (PXT*AP)    // one vs buffer in shorts (8704)

typedef __attribute__((ext_vector_type(8))) short bf16x8;
typedef __attribute__((ext_vector_type(4))) float f32x4;

static __device__ inline short f2bf(float f) {
  union { float f; unsigned u; } v; v.f = f;
  unsigned r = v.u + 0x7FFF + ((v.u >> 16) & 1);   // RNE
  return (short)(r >> 16);
}
static __device__ inline float bf_lo(unsigned u) {
  union { unsigned u; float f; } v; v.u = u << 16; return v.f;
}
static __device__ inline float bf_hi(unsigned u) {
  union { unsigned u; float f; } v; v.u = u & 0xffff0000u; return v.f;
}

// ---------------------------------------------------------------------------
// Kernel 1 (fused prep): [0,2048) transpose NCHW->BHWC bf16;
// [2048,2192) pack wOMs (A-frag swizzled, 32 oc zero-padded);
// [2192,2768) pack wAs (A-frag swizzled).
// ---------------------------------------------------------------------------
__global__ __launch_bounds__(256) void k_prep(const float* __restrict__ x,
    short* __restrict__ xbh,
    const float* __restrict__ w_off, const float* __restrict__ w_mod,
    short* __restrict__ wOMs, const float* __restrict__ w_reg,
    short* __restrict__ wAs) {
  __shared__ float tile[32][65];
  int blk = blockIdx.x;
  int t = threadIdx.x;
  if (blk < 2048) {                       // --- transpose ---
    int cg = blk & 3, y = (blk >> 2) & 63, b = blk >> 8;
#pragma unroll
    for (int j = 0; j < 8; ++j) {
      int idx = t + j * 256;
      int ci = idx >> 6, xi = idx & 63;
      tile[ci][xi] = x[(((b * CIN + cg * 32 + ci) * H + y) * W) + xi];
    }
    __syncthreads();
#pragma unroll
    for (int j = 0; j < 8; ++j) {
      int idx = t + j * 256;
      int xi = idx >> 5, ci = idx & 31;
      xbh[((b * H + y) * W + xi) * CIN + cg * 32 + ci] = f2bf(tile[ci][xi]);
    }
  } else if (blk < 2048 + 144) {          // --- wOMs pack (swizzled) ---
    int e = (blk - 2048) * 256 + t;       // tap*4096 + oc*128 + c  (36864)
    int tap = e >> 12, oc = (e >> 7) & 31, c = e & 127;
    float v = 0.f;
    if (oc < 18)      v = w_off[(oc * 128 + c) * 9 + tap];
    else if (oc < 27) v = w_mod[((oc - 18) * 128 + c) * 9 + tap];
    int kb = c >> 5, quad = (c >> 3) & 3, j = c & 7;
    int g = oc >> 4, l16 = oc & 15;
    int o = ((tap * 4 + kb) * 2 + g) * 512 + (quad * 16 + l16) * 8 + j;
    wOMs[o] = f2bf(v);
  } else {                                // --- wAs pack (swizzled) ---
    int e = (blk - 2192) * 256 + t;       // tap*16384 + oc*128 + c
    int tap = e >> 14, oc = (e >> 7) & 127, c = e & 127;
    int kb = c >> 5, quad = (c >> 3) & 3, j = c & 7;
    int g = oc >> 4, l16 = oc & 15;
    int o = ((tap * 4 + kb) * 8 + g) * 512 + (quad * 16 + l16) * 8 + j;
    wAs[o] = f2bf(w_reg[(oc * 128 + c) * 9 + tap]);
  }
}

// ---------------------------------------------------------------------------
// Kernel 2: FUSED offset/mask conv + deformable conv.  512 threads, 8 waves.
// R10: PXT 64.  Phase 1: wave = (px-half h = wv>>2, tap-group tg = wv&3,
// taps {tg, tg+4(,8)}); red unchanged at 31 KB.  Phase 2: wave = (ms oc-slice,
// nh px-half), acc[2][2] -> each A-frag feeds 2 n-tiles (VMEM instrs -36%).
// MFMA layouts (m89/m91): A[m=l16][k=quad*8+j], B[k=quad*8+j][n=l16],
//   D[m=quad*4+r][n=l16].
// ---------------------------------------------------------------------------
__global__ __launch_bounds__(512, 4) void k_deform(const short* __restrict__ xbh,
    const short* __restrict__ wOMs, const float* __restrict__ b_off,
    const float* __restrict__ b_mod, const short* __restrict__ wAs,
    float* __restrict__ out) {
  // red: 8 waves x 27 oc x pitch 36 floats = 31104 B
  // vs : 2 buffers x 64 px x 136 shorts    = 34816 B  (union)
  __shared__ __align__(16) char smem_u[2 * VSZ * 2];
  __shared__ __align__(16) float pw[PXT * 9 * 4]; // 9216 B {w00,w01,w10,w11}
  __shared__ __align__(16) int   pa[PXT * 9 * 4]; // 9216 B {a00,a01,a10,a11}
  float* red = (float*)smem_u;
  short* vs  = (short*)smem_u;

  int blk = blockIdx.x;
  int b = blk & 7, tile = blk >> 3;               // XCD swizzle
  int pix0 = tile * PXT;
  int t = threadIdx.x;
  int lane = t & 63;
  int wv = t >> 6;                                // 0..7
  int l16 = lane & 15, quad = lane >> 4;

  const short* xbB = xbh + (size_t)b * NPIX * CIN;

  // ===== Phase 1: offset/mask mini-GEMM =====
  // wave wv: px-half h = wv>>2 (32 px), taps {tg, tg+4} (+8 if tg==0)
  {
    int h = wv >> 2, tg = wv & 3;
    int pix0h = pix0 + h * 32;
    f32x4 acc_o[2][2] = {};
#pragma unroll
    for (int ti = 0; ti < 3; ++ti) {
      int tap = tg + ti * 4;
      if (tap > 8) break;                         // wave-uniform
      const short* wt = wOMs + tap * 4096;
      int dy = tap / 3 - 1, dx = tap % 3 - 1;
      int lin[2], val[2];
#pragma unroll
      for (int nt = 0; nt < 2; ++nt) {
        int gp = pix0h + nt * 16 + l16;
        int y = (gp >> 6) + dy, x = (gp & 63) + dx;
        int ok = ((unsigned)y < H) && ((unsigned)x < W);
        val[nt] = ok;
        lin[nt] = ok ? ((y << 6) + x) : 0;
      }
#pragma unroll
      for (int kb = 0; kb < 4; ++kb) {
        bf16x8 a0 = *(const bf16x8*)&wt[(kb * 2 + 0) * 512 + lane * 8];
        bf16x8 a1 = *(const bf16x8*)&wt[(kb * 2 + 1) * 512 + lane * 8];
#pragma unroll
        for (int nt = 0; nt < 2; ++nt) {
          bf16x8 bv = *(const bf16x8*)&xbB[(size_t)lin[nt] * CIN + kb * 32 + quad * 8];
          if (!val[nt]) bv = (bf16x8){};
          acc_o[0][nt] = __builtin_amdgcn_mfma_f32_16x16x32_bf16(a0, bv, acc_o[0][nt], 0, 0, 0);
          acc_o[1][nt] = __builtin_amdgcn_mfma_f32_16x16x32_bf16(a1, bv, acc_o[1][nt], 0, 0, 0);
        }
      }
    }
    // partials -> red[wv][oc][px_local]  (only oc<27 used)
#pragma unroll
    for (int mt = 0; mt < 2; ++mt)
#pragma unroll
      for (int nt = 0; nt < 2; ++nt)
#pragma unroll
        for (int r = 0; r < 4; ++r) {
          int oc = mt * 16 + quad * 4 + r;
          if (oc < 27) {
            int px = nt * 16 + l16;
            red[wv * (27 * RP) + oc * RP + px] = acc_o[mt][nt][r];
          }
        }
  }
  __syncthreads();

  // ===== reduce 4 waves per px-half + bias + sigmoid -> pw / pa =====
  for (int i = t; i < PXT * 9; i += 512) {        // 576 entries
    int tap = i % 9, p = i / 9;                   // p in 0..63
    int h = p >> 5, pl = p & 31;
    float dyv = b_off[2 * tap], dxv = b_off[2 * tap + 1], z = b_mod[tap];
#pragma unroll
    for (int w = 0; w < 4; ++w) {
      const float* rw = red + (4 * h + w) * (27 * RP);
      dyv += rw[(2 * tap) * RP + pl];
      dxv += rw[(2 * tap + 1) * RP + pl];
      z   += rw[(18 + tap) * RP + pl];
    }
    float m = 2.f / (1.f + expf(-z));
    int gp = pix0 + p;
    float py = (float)((gp >> 6) - 1 + tap / 3) + dyv;
    float pxx = (float)((gp & 63) - 1 + tap % 3) + dxv;
    float yf = floorf(py), xf = floorf(pxx);
    float wy = py - yf, wx = pxx - xf;
    int y0 = (int)yf, x0 = (int)xf;
    int y1 = y0 + 1, x1 = x0 + 1;
    float vy0 = ((unsigned)y0 < H) ? 1.f : 0.f;
    float vy1 = ((unsigned)y1 < H) ? 1.f : 0.f;
    float vx0 = ((unsigned)x0 < W) ? 1.f : 0.f;
    float vx1 = ((unsigned)x1 < W) ? 1.f : 0.f;
    int y0c = min(max(y0, 0), H - 1), y1c = min(max(y1, 0), H - 1);
    int x0c = min(max(x0, 0), W - 1), x1c = min(max(x1, 0), W - 1);
    *(float4*)&pw[i * 4] = make_float4((1.f - wy) * (1.f - wx) * m * vy0 * vx0,
                                       (1.f - wy) * wx * m * vy0 * vx1,
                                       wy * (1.f - wx) * m * vy1 * vx0,
                                       wy * wx * m * vy1 * vx1);
    *(int4*)&pa[i * 4] = make_int4(((y0c << 6) + x0c) << 7,
                                   ((y0c << 6) + x1c) << 7,
                                   ((y1c << 6) + x0c) << 7,
                                   ((y1c << 6) + x1c) << 7);
  }
  __syncthreads();   // pw/pa visible; red reads done (vs may alias)

  // ===== Phase 2: main deformable GEMM, double-buffered vs =====
  int ms = wv & 3, nh = wv >> 2;          // oc-slice, px-half (32 px)
  int cq = t & 7, ps = t >> 3;            // 16-ch group, pixel (0..63)
  int c0 = cq * 16;

  f32x4 acc[2][2] = {};

  for (int tap = 0; tap < 9; ++tap) {
    short* vbuf = vs + (tap & 1) * VSZ;

    // --- sample: 1 px x 16 ch per thread, 8 gathers of 16 B ---
    {
      int idx = (ps * 9 + tap) * 4;
      float4 wq = *(const float4*)&pw[idx];
      int4 aa = *(const int4*)&pa[idx];
      uint4 a_lo = *(const uint4*)&xbB[aa.x + c0];
      uint4 a_hi = *(const uint4*)&xbB[aa.x + c0 + 8];
      uint4 b_lo = *(const uint4*)&xbB[aa.y + c0];
      uint4 b_hi = *(const uint4*)&xbB[aa.y + c0 + 8];
      uint4 c_lo = *(const uint4*)&xbB[aa.z + c0];
      uint4 c_hi = *(const uint4*)&xbB[aa.z + c0 + 8];
      uint4 d_lo = *(const uint4*)&xbB[aa.w + c0];
      uint4 d_hi = *(const uint4*)&xbB[aa.w + c0 + 8];
      float s[16];
#pragma unroll
      for (int j = 0; j < 4; ++j) {
        unsigned ua = ((const unsigned*)&a_lo)[j];
        unsigned ub = ((const unsigned*)&b_lo)[j];
        unsigned uc = ((const unsigned*)&c_lo)[j];
        unsigned ud = ((const unsigned*)&d_lo)[j];
        s[2*j]   = fmaf(wq.w, bf_lo(ud), fmaf(wq.z, bf_lo(uc),
                   fmaf(wq.y, bf_lo(ub), wq.x * bf_lo(ua))));
        s[2*j+1] = fmaf(wq.w, bf_hi(ud), fmaf(wq.z, bf_hi(uc),
                   fmaf(wq.y, bf_hi(ub), wq.x * bf_hi(ua))));
      }
#pragma unroll
      for (int j = 0; j < 4; ++j) {
        unsigned ua = ((const unsigned*)&a_hi)[j];
        unsigned ub = ((const unsigned*)&b_hi)[j];
        unsigned uc = ((const unsigned*)&c_hi)[j];
        unsigned ud = ((const unsigned*)&d_hi)[j];
        s[8+2*j]   = fmaf(wq.w, bf_lo(ud), fmaf(wq.z, bf_lo(uc),
                     fmaf(wq.y, bf_lo(ub), wq.x * bf_lo(ua))));
        s[8+2*j+1] = fmaf(wq.w, bf_hi(ud), fmaf(wq.z, bf_hi(uc),
                     fmaf(wq.y, bf_hi(ub), wq.x * bf_hi(ua))));
      }
      uint4 p0, p1;
#pragma unroll
      for (int j = 0; j < 4; ++j) {
        __hip_bfloat162 h2 = __float22bfloat162_rn(make_float2(s[2*j], s[2*j+1]));
        ((unsigned*)&p0)[j] = *(unsigned*)&h2;
      }
#pragma unroll
      for (int j = 0; j < 4; ++j) {
        __hip_bfloat162 h2 = __float22bfloat162_rn(make_float2(s[8+2*j], s[8+2*j+1]));
        ((unsigned*)&p1)[j] = *(unsigned*)&h2;
      }
      *(uint4*)&vbuf[ps * AP + c0] = p0;
      *(uint4*)&vbuf[ps * AP + c0 + 8] = p1;
    }

    // --- A frags prefetch (in flight across barrier) ---
    const short* wtap = wAs + tap * 16384;
    bf16x8 af0[4], af1[4];
#pragma unroll
    for (int kb = 0; kb < 4; ++kb) {
      af0[kb] = *(const bf16x8*)&wtap[(kb * 8 + ms * 2) * 512 + lane * 8];
      af1[kb] = *(const bf16x8*)&wtap[(kb * 8 + ms * 2 + 1) * 512 + lane * 8];
    }
    __syncthreads();   // vbuf visible; other buffer free for tap+1

    // --- MFMA: 4 k-steps, 2 m-tiles x 2 n-tiles per wave ---
#pragma unroll
    for (int kb = 0; kb < 4; ++kb) {
      int kcol = kb * 32 + quad * 8;
      bf16x8 b0 = *(const bf16x8*)&vbuf[(nh * 32 + l16) * AP + kcol];
      bf16x8 b1 = *(const bf16x8*)&vbuf[(nh * 32 + 16 + l16) * AP + kcol];
      acc[0][0] = __builtin_amdgcn_mfma_f32_16x16x32_bf16(af0[kb], b0, acc[0][0], 0, 0, 0);
      acc[0][1] = __builtin_amdgcn_mfma_f32_16x16x32_bf16(af0[kb], b1, acc[0][1], 0, 0, 0);
      acc[1][0] = __builtin_amdgcn_mfma_f32_16x16x32_bf16(af1[kb], b0, acc[1][0], 0, 0, 0);
      acc[1][1] = __builtin_amdgcn_mfma_f32_16x16x32_bf16(af1[kb], b1, acc[1][1], 0, 0, 0);
    }
  }

  // epilogue: D[m=quad*4+r][n=l16] -> out[b][oc][pix]
  int oc_base = ms * 32;
#pragma unroll
  for (int mt = 0; mt < 2; ++mt)
#pragma unroll
    for (int nt = 0; nt < 2; ++nt)
#pragma unroll
      for (int r = 0; r < 4; ++r) {
        int oc = oc_base + mt * 16 + quad * 4 + r;
        int px = nh * 32 + nt * 16 + l16;
        out[(size_t)(b * COUT + oc) * NPIX + pix0 + px] = acc[mt][nt][r];
      }
}

// ---------------------------------------------------------------------------
extern "C" void kernel_launch(void* const* d_in, const int* in_sizes, int n_in,
                              void* d_out, int out_size, void* d_ws, size_t ws_size,
                              hipStream_t stream) {
  const float* x     = (const float*)d_in[0];
  const float* w_off = (const float*)d_in[1];
  const float* b_off = (const float*)d_in[2];
  const float* w_mod = (const float*)d_in[3];
  const float* b_mod = (const float*)d_in[4];
  const float* w_reg = (const float*)d_in[5];

  short* xbh  = (short*)d_ws;              // 4,194,304 bf16 (8 MB)
  short* wAs  = xbh + 4194304;             //   147,456 bf16 (swizzled)
  short* wOMs = wAs + 147456;              //    36,864 bf16 (swizzled)
  float* out  = (float*)d_out;

  k_prep<<<dim3(2768), 256, 0, stream>>>(x, xbh, w_off, w_mod, wOMs,
                                         w_reg, wAs);
  k_deform<<<dim3(NPIX / PXT * BATCH), 512, 0, stream>>>(
      xbh, wOMs, b_off, b_mod, wAs, out);
}

// Round 11
// 112.087 us; speedup vs baseline: 1.1704x; 1.0398x over previous
//
#include <hip/hip_runtime.h>
#include <hip/hip_bf16.h>
#include <math.h>

#define H 64
#define W 64
#define CIN 128
#define COUT 128
#define BATCH 8
#define NPIX (H*W)      // 4096
#define PXT 32          // pixels per k_deform block
#define AP  136         // vs pitch in bf16 (16B-aligned; 4-way on b128 reads ~ok)
#define RP  36          // red pitch (floats)
#define VSZ (PXT*AP)    // one vs buffer in shorts (4352)

typedef __attribute__((ext_vector_type(8))) short bf16x8;
typedef __attribute__((ext_vector_type(4))) float f32x4;
typedef __attribute__((ext_vector_type(16))) float f32x16;

static __device__ inline short f2bf(float f) {
  union { float f; unsigned u; } v; v.f = f;
  unsigned r = v.u + 0x7FFF + ((v.u >> 16) & 1);   // RNE
  return (short)(r >> 16);
}
static __device__ inline float bf_lo(unsigned u) {
  union { unsigned u; float f; } v; v.u = u << 16; return v.f;
}
static __device__ inline float bf_hi(unsigned u) {
  union { unsigned u; float f; } v; v.u = u & 0xffff0000u; return v.f;
}

// ---------------------------------------------------------------------------
// Kernel 1 (fused prep): [0,2048) transpose NCHW->BHWC bf16;
// [2048,2192) pack wOMs32; [2192,2768) pack wAs32.
// 32x32x16 A-frag packing: A[m=lane&31][k=(lane>>5)*8+j], k = kstep*16 + ...
//   elem (tap, kstep, lane, j) stored contiguously -> one 1 KB wave load.
// ---------------------------------------------------------------------------
__global__ __launch_bounds__(256) void k_prep(const float* __restrict__ x,
    short* __restrict__ xbh,
    const float* __restrict__ w_off, const float* __restrict__ w_mod,
    short* __restrict__ wOMs, const float* __restrict__ w_reg,
    short* __restrict__ wAs) {
  __shared__ float tile[32][65];
  int blk = blockIdx.x;
  int t = threadIdx.x;
  if (blk < 2048) {                       // --- transpose ---
    int cg = blk & 3, y = (blk >> 2) & 63, b = blk >> 8;
#pragma unroll
    for (int j = 0; j < 8; ++j) {
      int idx = t + j * 256;
      int ci = idx >> 6, xi = idx & 63;
      tile[ci][xi] = x[(((b * CIN + cg * 32 + ci) * H + y) * W) + xi];
    }
    __syncthreads();
#pragma unroll
    for (int j = 0; j < 8; ++j) {
      int idx = t + j * 256;
      int xi = idx >> 5, ci = idx & 31;
      xbh[((b * H + y) * W + xi) * CIN + cg * 32 + ci] = f2bf(tile[ci][xi]);
    }
  } else if (blk < 2048 + 144) {          // --- wOMs32 pack ---
    int e = (blk - 2048) * 256 + t;       // tap*4096 + oc*128 + c  (36864)
    int tap = e >> 12, oc = (e >> 7) & 31, c = e & 127;
    float v = 0.f;
    if (oc < 18)      v = w_off[(oc * 128 + c) * 9 + tap];
    else if (oc < 27) v = w_mod[((oc - 18) * 128 + c) * 9 + tap];
    int kstep = c >> 4, g = (c >> 3) & 1, j = c & 7;
    int lane = g * 32 + oc;
    int o = ((tap * 8 + kstep) * 64 + lane) * 8 + j;
    wOMs[o] = f2bf(v);
  } else {                                // --- wAs32 pack ---
    int e = (blk - 2192) * 256 + t;       // tap*16384 + oc*128 + c
    int tap = e >> 14, oc = (e >> 7) & 127, c = e & 127;
    int kstep = c >> 4, g = (c >> 3) & 1, j = c & 7;
    int ms = oc >> 5, m = oc & 31;
    int lane = g * 32 + m;
    int o = (((tap * 8 + kstep) * 4 + ms) * 64 + lane) * 8 + j;
    wAs[o] = f2bf(w_reg[(oc * 128 + c) * 9 + tap]);
  }
}

// ---------------------------------------------------------------------------
// Kernel 2: FUSED offset/mask + deformable conv.  512 threads, 8 waves.
// R11: mfma_f32_32x32x16_bf16 everywhere.
//   Phase 1: wave wv = tap {wv, wv+8}; one 32x32 tile covers 27oc x 32px;
//            8 k-steps/tap; partials -> red[8][27][RP].
//   Phase 2: wave = (ms = wv&3 oc-slice, ks = wv>>2 K-half); per tap each
//            wave: 4 A-frag loads + 4 MFMA; split-K reduced via redE at end.
// 32x32x16 layouts: A[m=lane&31][k=(lane>>5)*8+j] (probe: absmax sentinel),
//   C/D row=(r&3)+8*(r>>2)+4*(lane>>5), col=lane&31 [verified m74/m101].
// LDS: union(red 31.1K, vs-dbuf 17.4K, redE 16.9K) + pw 4.6K + pa 2.3K
//   = 38.0 KB -> 4 blocks/CU at grid 1024.
// ---------------------------------------------------------------------------
__global__ __launch_bounds__(512, 8) void k_deform(const short* __restrict__ xbh,
    const short* __restrict__ wOMs, const float* __restrict__ b_off,
    const float* __restrict__ b_mod, const short* __restrict__ wAs,
    float* __restrict__ out) {
  __shared__ __align__(16) char smem_u[31104];     // red | vs dbuf | redE
  __shared__ __align__(16) float  pw[PXT * 9 * 4]; // 4608 B
  __shared__ __align__(16) ushort pa4[PXT * 9 * 4];// 2304 B (pixel-linear)
  float* red  = (float*)smem_u;
  short* vs   = (short*)smem_u;
  float* redE = (float*)smem_u;

  int blk = blockIdx.x;
  int b = blk & 7, tile = blk >> 3;               // XCD swizzle
  int pix0 = tile * PXT;
  int t = threadIdx.x;
  int lane = t & 63;
  int wv = t >> 6;                                // 0..7
  int n32 = lane & 31, g = lane >> 5;

  const short* xbB = xbh + (size_t)b * NPIX * CIN;

  // ===== Phase 1: offset/mask mini-GEMM, wave = tap =====
  {
    f32x16 accO = {};
#pragma unroll
    for (int ti = 0; ti < 2; ++ti) {
      int tap = wv + ti * 8;
      if (tap > 8) break;                         // wave-uniform
      int dy = tap / 3 - 1, dx = tap % 3 - 1;
      int gp = pix0 + n32;
      int y = (gp >> 6) + dy, x = (gp & 63) + dx;
      int ok = ((unsigned)y < H) && ((unsigned)x < W);
      int lin = ok ? ((y << 6) + x) : 0;
      const short* wt = wOMs;
#pragma unroll
      for (int kstep = 0; kstep < 8; ++kstep) {
        bf16x8 a = *(const bf16x8*)&wt[((tap * 8 + kstep) * 64 + lane) * 8];
        int c0 = kstep * 16 + g * 8;
        bf16x8 bv = *(const bf16x8*)&xbB[(size_t)lin * CIN + c0];
        if (!ok) bv = (bf16x8){};
        accO = __builtin_amdgcn_mfma_f32_32x32x16_bf16(a, bv, accO, 0, 0, 0);
      }
    }
    // partials -> red[wv][oc][px]  (C/D: row=(r&3)+8*(r>>2)+4*g, col=n32)
#pragma unroll
    for (int r = 0; r < 16; ++r) {
      int row = (r & 3) + 8 * (r >> 2) + 4 * g;
      if (row < 27) red[wv * (27 * RP) + row * RP + n32] = accO[r];
    }
  }
  __syncthreads();

  // ===== reduce 8 partials + bias + sigmoid -> pw / pa4 =====
  for (int i = t; i < PXT * 9; i += 512) {        // i = p*9 + tap
    int tap = i % 9, p = i / 9;
    float dyv = b_off[2 * tap], dxv = b_off[2 * tap + 1], z = b_mod[tap];
#pragma unroll
    for (int w = 0; w < 8; ++w) {
      const float* rw = red + w * (27 * RP);
      dyv += rw[(2 * tap) * RP + p];
      dxv += rw[(2 * tap + 1) * RP + p];
      z   += rw[(18 + tap) * RP + p];
    }
    float m = 2.f / (1.f + expf(-z));
    int gp = pix0 + p;
    float py = (float)((gp >> 6) - 1 + tap / 3) + dyv;
    float pxx = (float)((gp & 63) - 1 + tap % 3) + dxv;
    float yf = floorf(py), xf = floorf(pxx);
    float wy = py - yf, wx = pxx - xf;
    int y0 = (int)yf, x0 = (int)xf;
    int y1 = y0 + 1, x1 = x0 + 1;
    float vy0 = ((unsigned)y0 < H) ? 1.f : 0.f;
    float vy1 = ((unsigned)y1 < H) ? 1.f : 0.f;
    float vx0 = ((unsigned)x0 < W) ? 1.f : 0.f;
    float vx1 = ((unsigned)x1 < W) ? 1.f : 0.f;
    int y0c = min(max(y0, 0), H - 1), y1c = min(max(y1, 0), H - 1);
    int x0c = min(max(x0, 0), W - 1), x1c = min(max(x1, 0), W - 1);
    *(float4*)&pw[i * 4] = make_float4((1.f - wy) * (1.f - wx) * m * vy0 * vx0,
                                       (1.f - wy) * wx * m * vy0 * vx1,
                                       wy * (1.f - wx) * m * vy1 * vx0,
                                       wy * wx * m * vy1 * vx1);
    pa4[i * 4 + 0] = (ushort)((y0c << 6) + x0c);
    pa4[i * 4 + 1] = (ushort)((y0c << 6) + x1c);
    pa4[i * 4 + 2] = (ushort)((y1c << 6) + x0c);
    pa4[i * 4 + 3] = (ushort)((y1c << 6) + x1c);
  }
  __syncthreads();   // pw/pa visible; red reads done (vs may alias)

  // ===== Phase 2: deformable GEMM, 32x32x16, split-K over 2 waves =====
  int ms = wv & 3, ks = wv >> 2;
  int cq = t & 15, ps = t >> 4;           // 8-ch group, pixel (0..31)
  int c0s = cq * 8;

  f32x16 acc = {};

  for (int tap = 0; tap < 9; ++tap) {
    short* vbuf = vs + (tap & 1) * VSZ;

    // --- sample: 1 px x 8 ch per thread, 4 corner gathers of 16 B ---
    {
      int idx = (ps * 9 + tap) * 4;
      float4 wq = *(const float4*)&pw[idx];
      int a00 = (int)pa4[idx]     * CIN;
      int a01 = (int)pa4[idx + 1] * CIN;
      int a10 = (int)pa4[idx + 2] * CIN;
      int a11 = (int)pa4[idx + 3] * CIN;
      uint4 u00 = *(const uint4*)&xbB[a00 + c0s];
      uint4 u01 = *(const uint4*)&xbB[a01 + c0s];
      uint4 u10 = *(const uint4*)&xbB[a10 + c0s];
      uint4 u11 = *(const uint4*)&xbB[a11 + c0s];
      uint4 packed;
#pragma unroll
      for (int j = 0; j < 4; ++j) {
        unsigned ua = ((const unsigned*)&u00)[j];
        unsigned ub = ((const unsigned*)&u01)[j];
        unsigned uc = ((const unsigned*)&u10)[j];
        unsigned ud = ((const unsigned*)&u11)[j];
        float s0 = fmaf(wq.w, bf_lo(ud), fmaf(wq.z, bf_lo(uc),
                   fmaf(wq.y, bf_lo(ub), wq.x * bf_lo(ua))));
        float s1 = fmaf(wq.w, bf_hi(ud), fmaf(wq.z, bf_hi(uc),
                   fmaf(wq.y, bf_hi(ub), wq.x * bf_hi(ua))));
        __hip_bfloat162 h2 = __float22bfloat162_rn(make_float2(s0, s1));
        ((unsigned*)&packed)[j] = *(unsigned*)&h2;
      }
      *(uint4*)&vbuf[ps * AP + c0s] = packed;
    }

    // --- A frags: 4 k-steps, contiguous 1 KB wave loads ---
    bf16x8 af[4];
#pragma unroll
    for (int i = 0; i < 4; ++i) {
      int kstep = ks * 4 + i;
      af[i] = *(const bf16x8*)&wAs[(((tap * 8 + kstep) * 4 + ms) * 64 + lane) * 8];
    }
    __syncthreads();   // vbuf visible; other buffer free for tap+1

    // --- MFMA: 4 k-steps of 32x32x16 ---
#pragma unroll
    for (int i = 0; i < 4; ++i) {
      int kstep = ks * 4 + i;
      int c0 = kstep * 16 + g * 8;
      bf16x8 bfr = *(const bf16x8*)&vbuf[n32 * AP + c0];
      acc = __builtin_amdgcn_mfma_f32_32x32x16_bf16(af[i], bfr, acc, 0, 0, 0);
    }
  }

  // ===== epilogue: split-K reduce via redE, then store =====
  __syncthreads();   // all MFMA vs-reads done before redE aliases
  if (ks == 1) {
#pragma unroll
    for (int r = 0; r < 16; ++r) {
      int row = (r & 3) + 8 * (r >> 2) + 4 * g;
      redE[ms * (32 * 33) + row * 33 + n32] = acc[r];
    }
  }
  __syncthreads();
  if (ks == 0) {
#pragma unroll
    for (int r = 0; r < 16; ++r) {
      int row = (r & 3) + 8 * (r >> 2) + 4 * g;
      float v = acc[r] + redE[ms * (32 * 33) + row * 33 + n32];
      out[(size_t)(b * COUT + ms * 32 + row) * NPIX + pix0 + n32] = v;
    }
  }
}

// ---------------------------------------------------------------------------
extern "C" void kernel_launch(void* const* d_in, const int* in_sizes, int n_in,
                              void* d_out, int out_size, void* d_ws, size_t ws_size,
                              hipStream_t stream) {
  const float* x     = (const float*)d_in[0];
  const float* w_off = (const float*)d_in[1];
  const float* b_off = (const float*)d_in[2];
  const float* w_mod = (const float*)d_in[3];
  const float* b_mod = (const float*)d_in[4];
  const float* w_reg = (const float*)d_in[5];

  short* xbh  = (short*)d_ws;              // 4,194,304 bf16 (8 MB)
  short* wAs  = xbh + 4194304;             //   147,456 bf16 (32x32 swizzled)
  short* wOMs = wAs + 147456;              //    36,864 bf16 (32x32 swizzled)
  float* out  = (float*)d_out;

  k_prep<<<dim3(2768), 256, 0, stream>>>(x, xbh, w_off, w_mod, wOMs,
                                         w_reg, wAs);
  k_deform<<<dim3(NPIX / PXT * BATCH), 512, 0, stream>>>(
      xbh, wOMs, b_off, b_mod, wAs, out);
}